// Round 3
// baseline (10090.913 us; speedup 1.0000x reference)
//
#include <hip/hip_runtime.h>
#include <math.h>

#define E 256
#define Hh 512

typedef __attribute__((ext_vector_type(8))) short short8;
typedef __attribute__((ext_vector_type(4))) float f32x4;

// R15: persistent LSTM via PLAIN launch (R13/R14's hipLaunchCooperativeKernel
// silently no-opped under graph capture -> identical deterministic failures).
// 336 blocks co-resident by capacity math (<=2 blocks/CU, LDS 64KB/CU,
// launch_bounds(256,2) caps VGPR<=256). h exchange guarded by per-mb-group
// 16-block counter barrier (device-scope acquire/release + threadfence).
// Compute body verbatim R12-proven; c in registers; bounded spin (no hangs).

struct LstmP {
  const int* ids;
  const float* emb;            // f32 embedding table (cvt to bf16 in-kernel)
  const unsigned short* Wih;   // bf16 ws cache [2048,256]
  const unsigned short* Whh;   // bf16 ws cache [2048,512]
  const float* bias;           // f32 [2048]
  unsigned short* h0;          // bf16 double buffer base (2 * nh)
  float* c;                    // f32 [N,512] final-c output
  int T;
  int nh;                      // N*512
};

__device__ unsigned g_cnt[32];   // per-group step counters (sc 0-9, cm 10-19, is 20)

__device__ __forceinline__ float bf2f(unsigned short x){
  union { unsigned u; float f; } v; v.u = ((unsigned)x) << 16; return v.f;
}
__device__ __forceinline__ unsigned short f2bf(float f){
  union { float f; unsigned u; } v; v.f = f;
  unsigned u = v.u;
  return (unsigned short)((u + 0x7fffu + ((u >> 16) & 1u)) >> 16);
}
__device__ __forceinline__ short8 cvt8(const float* p){
  f32x4 x = *(const f32x4*)p;
  f32x4 y = *(const f32x4*)(p + 4);
  short8 r;
  r[0]=(short)f2bf(x[0]); r[1]=(short)f2bf(x[1]); r[2]=(short)f2bf(x[2]); r[3]=(short)f2bf(x[3]);
  r[4]=(short)f2bf(y[0]); r[5]=(short)f2bf(y[1]); r[6]=(short)f2bf(y[2]); r[7]=(short)f2bf(y[3]);
  return r;
}
__device__ __forceinline__ float sigm(float x){ return 1.0f/(1.0f + expf(-x)); }

__global__ void zero_ws_kernel(uint4* p, int n){
  int i = blockIdx.x*256 + threadIdx.x;
  if (i < n){ uint4 z; z.x=0u; z.y=0u; z.z=0u; z.w=0u; p[i]=z; }
}

__global__ void zero_cnt_kernel(){
  if (threadIdx.x < 32) g_cnt[threadIdx.x] = 0u;
}

// f32 -> bf16 (RNE), 8 elems/thread. (R3-proven cache bit-match.)
__global__ __launch_bounds__(256) void cvt_kernel(const float* src, unsigned short* dst, int n8){
  int i = blockIdx.x*256 + threadIdx.x;
  if (i < n8){
    *(short8*)(dst + (size_t)i*8) = cvt8(src + (size_t)i*8);
  }
}

// Persistent kernel: block = one (lstm, mb, jt) tile for all T steps.
// Per step: phase1 (emb x Wih, no h dep) -> group wait (h(t) ready) -> phase2
// (h x Whh) -> zb exchange -> epilogue (c in regs, h_out bf16) -> fence+release.
__global__ __launch_bounds__(256, 2) void lstm_persist(LstmP sc, LstmP cm, LstmP is_)
{
  __shared__ float zb[4][64][32];   // 32 KB; col-swizzle keeps LDS <=2-way (free)
  LstmP P; int tile, grp;
  {
    int idx = blockIdx.x;
    if (idx < 160){ P = sc;  tile = idx;        grp = tile >> 4; }
    else if (idx < 320){ P = cm;  tile = idx - 160;  grp = 10 + (tile >> 4); }
    else { P = is_; tile = idx - 320;  grp = 20; }
  }
  const int tid  = threadIdx.x;
  const int w    = tid >> 6;       // gate 0..3 = i,f,g,o
  const int lane = tid & 63;
  const int l15  = lane & 15;
  const int q    = lane >> 4;
  const int mb = tile >> 4, jt = tile & 15;
  const int m0 = mb*64, j0 = jt*32;
  const int T = P.T;
  unsigned* cgp = &g_cnt[grp];

  const int* idrow[4];             // ids row per A-fragment row
  int hoff[4];                     // h element offset per A-fragment row
  #pragma unroll
  for (int mi=0; mi<4; ++mi){
    int m = m0 + mi*16 + l15;
    idrow[mi] = P.ids + (size_t)m*T;
    hoff[mi]  = m*Hh + q*8;
  }
  const unsigned short* bp1[2];    // bf16 Wih rows (B row = gate unit = l15)
  const unsigned short* bp2[2];
  float bv[2];
  #pragma unroll
  for (int ni=0; ni<2; ++ni){
    int n = w*Hh + j0 + ni*16 + l15;
    bp1[ni] = P.Wih + (size_t)n*E  + q*8;
    bp2[ni] = P.Whh + (size_t)n*Hh + q*8;
    bv[ni]  = P.bias[n];
  }

  float cc[8];                     // persistent cell state (epilogue-mapped)
  #pragma unroll
  for (int i=0;i<8;++i) cc[i] = 0.f;

  for (int t = 0; t < T; ++t){
    const unsigned short* h_in  = P.h0 + (size_t)(t&1)*P.nh;
    unsigned short*       h_out = P.h0 + (size_t)((t+1)&1)*P.nh;

    f32x4 acc[4][2];
    #pragma unroll
    for (int i=0;i<4;++i)
      #pragma unroll
      for (int j=0;j<2;++j) acc[i][j] = (f32x4){0.f,0.f,0.f,0.f};

    // Phase 1: K=0..255, x = emb (cvt f32->bf16), W = Wih. No h dependence:
    // runs BEFORE the group wait to hide sync latency.
    const float* ap1[4];
    #pragma unroll
    for (int mi=0; mi<4; ++mi){
      int id = idrow[mi][t];
      ap1[mi] = P.emb + (size_t)id*E + q*8;
    }
    for (int kc=0; kc<8; ++kc){
      short8 a[4], b[2];
      #pragma unroll
      for (int mi=0;mi<4;++mi) a[mi] = cvt8(ap1[mi] + kc*32);
      #pragma unroll
      for (int ni=0;ni<2;++ni) b[ni] = *(const short8*)(bp1[ni] + kc*32);
      #pragma unroll
      for (int mi=0;mi<4;++mi)
        #pragma unroll
        for (int ni=0;ni<2;++ni)
          acc[mi][ni] = __builtin_amdgcn_mfma_f32_16x16x32_bf16(a[mi], b[ni], acc[mi][ni], 0,0,0);
    }

    // Wait for h(t): all 16 group blocks released step t-1 => counter >= 16*t.
    // t==0: h is all zeros -> phase 2 contributes exact zeros, skip it.
    if (t > 0){
      if (tid == 0){
        unsigned tgt = 16u * (unsigned)t;
        long guard = 0;
        while (__hip_atomic_load(cgp, __ATOMIC_ACQUIRE, __HIP_MEMORY_SCOPE_AGENT) < tgt){
          __builtin_amdgcn_s_sleep(1);
          if (++guard > 50000000L) break;   // convert protocol bug -> wrong answer, not hang
        }
      }
      __syncthreads();
      __threadfence();   // acquire side: order/invalidate before h reads (all threads)

      // Phase 2: K=256..767, x = h (bf16), W = Whh
      for (int kc=0; kc<16; ++kc){
        short8 a[4], b[2];
        #pragma unroll
        for (int mi=0;mi<4;++mi) a[mi] = *(const short8*)(h_in + hoff[mi] + kc*32);
        #pragma unroll
        for (int ni=0;ni<2;++ni) b[ni] = *(const short8*)(bp2[ni] + kc*32);
        #pragma unroll
        for (int mi=0;mi<4;++mi)
          #pragma unroll
          for (int ni=0;ni<2;++ni)
            acc[mi][ni] = __builtin_amdgcn_mfma_f32_16x16x32_bf16(a[mi], b[ni], acc[mi][ni], 0,0,0);
      }
    }

    // C/D layout (m89-verified): row = q*4+r, col = l15; swizzled store (2-way max)
    #pragma unroll
    for (int mi=0;mi<4;++mi)
      #pragma unroll
      for (int ni=0;ni<2;++ni)
        #pragma unroll
        for (int r=0;r<4;++r){
          int m = mi*16 + q*4 + r;
          int col = (ni*16 + l15 + q*8) & 31;
          zb[w][m][col] = acc[mi][ni][r] + bv[ni];
        }
    __syncthreads();

    #pragma unroll
    for (int i=0;i<8;++i){
      int e = tid + 256*i;
      int m = e >> 5, j = e & 31;
      int cs = (j + ((m>>2)&3)*8) & 31;       // matching swizzled load
      float zi = zb[0][m][cs], zf = zb[1][m][cs], zg = zb[2][m][cs], zo = zb[3][m][cs];
      float cn = sigm(zf)*cc[i] + sigm(zi)*tanhf(zg);
      float hn = sigm(zo)*tanhf(cn);
      cc[i] = cn;
      h_out[(size_t)(m0+m)*Hh + j0 + j] = f2bf(hn);
    }

    // Release step t: h_out stores -> fence -> block barrier -> tid0 release-add.
    // (The barrier also guards zb reuse at step t+1.)
    __threadfence();
    __syncthreads();
    if (tid == 0)
      __hip_atomic_fetch_add(cgp, 1u, __ATOMIC_RELEASE, __HIP_MEMORY_SCOPE_AGENT);
  }

  // Final c to global for out_kernel (kernel boundary orders vs out_kernel).
  #pragma unroll
  for (int i=0;i<8;++i){
    int e = tid + 256*i;
    int m = e >> 5, j = e & 31;
    P.c[(size_t)(m0+m)*Hh + j0 + j] = cc[i];
  }
}

// Output kernel, parallel rewrite. 256 blocks: (b, kind, u-half). v-row in LDS,
// hm via shfl-reduce (1 barrier), u-dot with 4 independent accumulators.
__global__ __launch_bounds__(256) void out_kernel(
    const unsigned short* hsc, const unsigned short* hcm, const unsigned short* his,
    const float* csc, const float* ccm, const float* cis,
    const float* Wmh, const float* bmh, const float* Wmc, const float* bmc,
    const float* Wfh, const float* bfh, const float* Wfc, const float* bfc,
    float* out)
{
  const int b    = blockIdx.x >> 2;
  const int kind = (blockIdx.x >> 1) & 1;
  const int half = blockIdx.x & 1;
  const int tid  = threadIdx.x;
  const int w = tid >> 6, lane = tid & 63;
  const float* Wm = kind ? Wmc : Wmh;
  const float* bm = kind ? bmc : bmh;
  const float* Wf = kind ? Wfc : Wfh;
  const float* bf = kind ? bfc : bfh;

  __shared__ float vis[512];
  __shared__ float wred[10][4];
  __shared__ float hmb[10];

  for (int k = tid; k < 512; k += 256)
    vis[k] = kind ? cis[(size_t)b*512 + k] : bf2f(his[(size_t)b*512 + k]);

  float pn[10];
  #pragma unroll
  for (int nc=0; nc<10; ++nc){
    size_t n = (size_t)b*10 + nc;
    float a = 0.f;
    #pragma unroll
    for (int kk=0; kk<2; ++kk){
      int k = tid + kk*256;
      float v1 = kind ? csc[n*512+k] : bf2f(hsc[n*512+k]);
      float v2 = kind ? ccm[n*512+k] : bf2f(hcm[n*512+k]);
      a += Wm[k]*v1 + Wm[512+k]*v2;
    }
    pn[nc] = a;
  }
  #pragma unroll
  for (int nc=0; nc<10; ++nc){
    float v = pn[nc];
    #pragma unroll
    for (int off=32; off; off>>=1) v += __shfl_down(v, off);
    if (lane == 0) wred[nc][w] = v;
  }
  __syncthreads();
  if (tid < 10) hmb[tid] = wred[tid][0] + wred[tid][1] + wred[tid][2] + wred[tid][3] + bm[0];
  __syncthreads();

  const int u = tid + 256*half;
  const float* wr = Wf + (size_t)u*522;
  float a0 = bf[u], a1 = 0.f, a2 = 0.f, a3 = 0.f;
  #pragma unroll
  for (int k=0; k<10; ++k) a0 += wr[k]*hmb[k];
  #pragma unroll 4
  for (int k=0; k<512; k+=4){
    a0 += wr[10+k] * vis[k];
    a1 += wr[11+k] * vis[k+1];
    a2 += wr[12+k] * vis[k+2];
    a3 += wr[13+k] * vis[k+3];
  }
  out[(size_t)kind*32768 + (size_t)b*512 + u] = (a0+a1) + (a2+a3);
}

extern "C" void kernel_launch(void* const* d_in, const int* in_sizes, int n_in,
                              void* d_out, int out_size, void* d_ws, size_t ws_size,
                              hipStream_t stream) {
  const int* comments = (const int*)d_in[0];
  const int* cm_ids   = (const int*)d_in[1];
  const int* issue    = (const int*)d_in[2];
  const float* emb_sc = (const float*)d_in[3];
  const float* emb_cm = (const float*)d_in[4];
  const float* emb_is = (const float*)d_in[5];
  const float* Wih_sc = (const float*)d_in[6];
  const float* Whh_sc = (const float*)d_in[7];
  const float* b_sc   = (const float*)d_in[8];
  const float* Wih_cm = (const float*)d_in[9];
  const float* Whh_cm = (const float*)d_in[10];
  const float* b_cm   = (const float*)d_in[11];
  const float* Wih_is = (const float*)d_in[12];
  const float* Whh_is = (const float*)d_in[13];
  const float* b_is   = (const float*)d_in[14];
  const float* Wmh = (const float*)d_in[15];
  const float* bmh = (const float*)d_in[16];
  const float* Wmc = (const float*)d_in[17];
  const float* bmc = (const float*)d_in[18];
  const float* Wfh = (const float*)d_in[19];
  const float* bfh = (const float*)d_in[20];
  const float* Wfc = (const float*)d_in[21];
  const float* bfc = (const float*)d_in[22];

  // Workspace (14.94 MB total == R3's proven extent; layout unchanged)
  char* p = (char*)d_ws;
  unsigned short* hb_sc = (unsigned short*)p; p += (size_t)2*640*512*2;
  unsigned short* hb_cm = (unsigned short*)p; p += (size_t)2*640*512*2;
  unsigned short* hb_is = (unsigned short*)p; p += (size_t)2*64*512*2;
  float* c_sc = (float*)p; p += (size_t)640*512*4;
  float* c_cm = (float*)p; p += (size_t)640*512*4;
  float* c_is = (float*)p; p += (size_t)64*512*4;
  size_t zero_bytes = (size_t)(p - (char*)d_ws);
  unsigned short* Wih_sc_b = (unsigned short*)p; p += (size_t)2048*256*2;
  unsigned short* Whh_sc_b = (unsigned short*)p; p += (size_t)2048*512*2;
  unsigned short* Wih_cm_b = (unsigned short*)p; p += (size_t)2048*256*2;
  unsigned short* Whh_cm_b = (unsigned short*)p; p += (size_t)2048*512*2;
  unsigned short* Wih_is_b = (unsigned short*)p; p += (size_t)2048*256*2;
  unsigned short* Whh_is_b = (unsigned short*)p; p += (size_t)2048*512*2;

  int n4 = (int)(zero_bytes/16);
  zero_ws_kernel<<<(n4+255)/256, 256, 0, stream>>>((uint4*)d_ws, n4);
  zero_cnt_kernel<<<1, 64, 0, stream>>>();

  const int nih8 = 2048*256/8, nhh8 = 2048*512/8;
  cvt_kernel<<<(nih8+255)/256, 256, 0, stream>>>(Wih_sc, Wih_sc_b, nih8);
  cvt_kernel<<<(nhh8+255)/256, 256, 0, stream>>>(Whh_sc, Whh_sc_b, nhh8);
  cvt_kernel<<<(nih8+255)/256, 256, 0, stream>>>(Wih_cm, Wih_cm_b, nih8);
  cvt_kernel<<<(nhh8+255)/256, 256, 0, stream>>>(Whh_cm, Whh_cm_b, nhh8);
  cvt_kernel<<<(nih8+255)/256, 256, 0, stream>>>(Wih_is, Wih_is_b, nih8);
  cvt_kernel<<<(nhh8+255)/256, 256, 0, stream>>>(Whh_is, Whh_is_b, nhh8);

  LstmP Psc = { comments, emb_sc, Wih_sc_b, Whh_sc_b, b_sc, hb_sc, c_sc, 128, 640*512 };
  LstmP Pcm = { cm_ids,   emb_cm, Wih_cm_b, Whh_cm_b, b_cm, hb_cm, c_cm,  64, 640*512 };
  LstmP Pis = { issue,    emb_is, Wih_is_b, Whh_is_b, b_is, hb_is, c_is,  32,  64*512 };
  lstm_persist<<<336, 256, 0, stream>>>(Psc, Pcm, Pis);

  // Final h states in buffer 0 for all three (T even for sc/cm/is).
  out_kernel<<<256, 256, 0, stream>>>(hb_sc, hb_cm, hb_is, c_sc, c_cm, c_is,
                                      Wmh, bmh, Wmc, bmc, Wfh, bfh, Wfc, bfc,
                                      (float*)d_out);
}

// Round 4
// 4733.439 us; speedup vs baseline: 2.1318x; 2.1318x over previous
//
#include <hip/hip_runtime.h>
#include <math.h>

#define E 256
#define Hh 512

typedef __attribute__((ext_vector_type(8))) short short8;
typedef __attribute__((ext_vector_type(4))) float f32x4;

// R16: persistent LSTM without cache-wide fences. R15's __threadfence pair
// (agent acq/rel -> buffer_inv/wbl2) invalidated all L2 weight lines every
// step -> 1.04 GB HBM refetch (measured). Replaced by per-instruction
// device-coherent h traffic: h stores = packed relaxed-agent atomic dwords
// (write-through, sc0 sc1); h loads = relaxed-agent atomic dwords staged to
// LDS once per block per step. Weights/emb stay normally cached, never
// invalidated. hs(64KB) overlays zb(32KB) in disjoint phases -> 2 blocks/CU,
// 336 blocks co-resident. Release = waitcnt vmcnt(0) + barrier + relaxed add.

struct LstmP {
  const int* ids;
  const float* emb;            // f32 embedding table (cvt to bf16 in-kernel)
  const unsigned short* Wih;   // bf16 ws cache [2048,256]
  const unsigned short* Whh;   // bf16 ws cache [2048,512]
  const float* bias;           // f32 [2048]
  unsigned short* h0;          // bf16 double buffer base (2 * nh)
  float* c;                    // f32 [N,512] final-c output
  int T;
  int nh;                      // N*512
};

__device__ unsigned g_cnt[21*32];   // per-group step counters, 128B apart

__device__ __forceinline__ float bf2f(unsigned short x){
  union { unsigned u; float f; } v; v.u = ((unsigned)x) << 16; return v.f;
}
__device__ __forceinline__ unsigned short f2bf(float f){
  union { float f; unsigned u; } v; v.f = f;
  unsigned u = v.u;
  return (unsigned short)((u + 0x7fffu + ((u >> 16) & 1u)) >> 16);
}
__device__ __forceinline__ short8 cvt8(const float* p){
  f32x4 x = *(const f32x4*)p;
  f32x4 y = *(const f32x4*)(p + 4);
  short8 r;
  r[0]=(short)f2bf(x[0]); r[1]=(short)f2bf(x[1]); r[2]=(short)f2bf(x[2]); r[3]=(short)f2bf(x[3]);
  r[4]=(short)f2bf(y[0]); r[5]=(short)f2bf(y[1]); r[6]=(short)f2bf(y[2]); r[7]=(short)f2bf(y[3]);
  return r;
}
__device__ __forceinline__ float sigm(float x){ return 1.0f/(1.0f + expf(-x)); }

__global__ void zero_ws_kernel(uint4* p, int n){
  int i = blockIdx.x*256 + threadIdx.x;
  if (i < n){ uint4 z; z.x=0u; z.y=0u; z.z=0u; z.w=0u; p[i]=z; }
}

__global__ void zero_cnt_kernel(){
  for (int i = threadIdx.x; i < 21*32; i += 256) g_cnt[i] = 0u;
}

// f32 -> bf16 (RNE), 8 elems/thread. (R3-proven cache bit-match.)
__global__ __launch_bounds__(256) void cvt_kernel(const float* src, unsigned short* dst, int n8){
  int i = blockIdx.x*256 + threadIdx.x;
  if (i < n8){
    *(short8*)(dst + (size_t)i*8) = cvt8(src + (size_t)i*8);
  }
}

// Persistent kernel: block = one (lstm, mb, jt) tile for all T steps.
// Per step: phase1 (emb x Wih) -> group wait -> coherent h stage to LDS ->
// phase2 (h x Whh from LDS) -> zb exchange (overlaid LDS) -> epilogue
// (c in regs, packed coherent h store) -> vmcnt drain -> barrier -> release.
__global__ __launch_bounds__(256, 2) void lstm_persist(LstmP sc, LstmP cm, LstmP is_)
{
  __shared__ unsigned short hs[64][512];          // 64 KB; also overlaid as zb
  float (*zb)[64][32] = (float(*)[64][32])hs;     // zb[4][64][32] = 32 KB prefix

  LstmP P; int tile, grp;
  {
    int idx = blockIdx.x;
    if (idx < 160){ P = sc;  tile = idx;        grp = tile >> 4; }
    else if (idx < 320){ P = cm;  tile = idx - 160;  grp = 10 + (tile >> 4); }
    else { P = is_; tile = idx - 320;  grp = 20; }
  }
  const int tid  = threadIdx.x;
  const int w    = tid >> 6;       // gate 0..3 = i,f,g,o
  const int lane = tid & 63;
  const int l15  = lane & 15;
  const int q    = lane >> 4;
  const int mb = tile >> 4, jt = tile & 15;
  const int m0 = mb*64, j0 = jt*32;
  const int T = P.T;
  unsigned* cgp = &g_cnt[grp*32];
  const int xr = (l15 & 7) << 3;   // hs row-XOR swizzle (per-lane const)

  const int* idrow[4];             // ids row per A-fragment row
  #pragma unroll
  for (int mi=0; mi<4; ++mi){
    int m = m0 + mi*16 + l15;
    idrow[mi] = P.ids + (size_t)m*T;
  }
  const unsigned short* bp1[2];    // bf16 Wih rows (B row = gate unit = l15)
  const unsigned short* bp2[2];
  float bv[2];
  #pragma unroll
  for (int ni=0; ni<2; ++ni){
    int n = w*Hh + j0 + ni*16 + l15;
    bp1[ni] = P.Wih + (size_t)n*E  + q*8;
    bp2[ni] = P.Whh + (size_t)n*Hh + q*8;
    bv[ni]  = P.bias[n];
  }

  float cc[8];                     // persistent cell state (epilogue-mapped)
  #pragma unroll
  for (int i=0;i<8;++i) cc[i] = 0.f;

  for (int t = 0; t < T; ++t){
    const unsigned short* h_in  = P.h0 + (size_t)(t&1)*P.nh;
    unsigned short*       h_out = P.h0 + (size_t)((t+1)&1)*P.nh;

    f32x4 acc[4][2];
    #pragma unroll
    for (int i=0;i<4;++i)
      #pragma unroll
      for (int j=0;j<2;++j) acc[i][j] = (f32x4){0.f,0.f,0.f,0.f};

    // Phase 1: K=0..255, x = emb (cvt f32->bf16), W = Wih. No h dependence:
    // runs BEFORE the group wait to hide sync latency.
    const float* ap1[4];
    #pragma unroll
    for (int mi=0; mi<4; ++mi){
      int id = idrow[mi][t];
      ap1[mi] = P.emb + (size_t)id*E + q*8;
    }
    for (int kc=0; kc<8; ++kc){
      short8 a[4], b[2];
      #pragma unroll
      for (int mi=0;mi<4;++mi) a[mi] = cvt8(ap1[mi] + kc*32);
      #pragma unroll
      for (int ni=0;ni<2;++ni) b[ni] = *(const short8*)(bp1[ni] + kc*32);
      #pragma unroll
      for (int mi=0;mi<4;++mi)
        #pragma unroll
        for (int ni=0;ni<2;++ni)
          acc[mi][ni] = __builtin_amdgcn_mfma_f32_16x16x32_bf16(a[mi], b[ni], acc[mi][ni], 0,0,0);
    }

    // Wait for h(t): all 16 group blocks released step t-1 => counter >= 16*t.
    // t==0: h is all zeros -> phase 2 contributes exact zeros, skip it.
    if (t > 0){
      if (tid == 0){
        unsigned tgt = 16u * (unsigned)t;
        long guard = 0;
        while (__hip_atomic_load(cgp, __ATOMIC_RELAXED, __HIP_MEMORY_SCOPE_AGENT) < tgt){
          __builtin_amdgcn_s_sleep(1);
          if (++guard > 2000000L) break;   // convert protocol bug -> wrong answer, not hang
        }
      }
      __syncthreads();
      asm volatile("" ::: "memory");       // compiler-only fence (no cache ops)

      // Stage h rows m0..m0+63 into LDS via device-coherent dword loads
      // (sc0 sc1: bypass L1/L2, read the coherence point; no invalidation).
      {
        const unsigned* src = (const unsigned*)(h_in + (size_t)m0*Hh);
        #pragma unroll 8
        for (int d = tid; d < 64*256; d += 256){
          unsigned v = __hip_atomic_load(src + d, __ATOMIC_RELAXED, __HIP_MEMORY_SCOPE_AGENT);
          int row = d >> 8, cole = (d & 255) << 1;
          *(unsigned*)&hs[row][cole ^ ((row & 7) << 3)] = v;
        }
      }
      __syncthreads();

      // Phase 2: K=256..767, x = h (bf16, from swizzled LDS), W = Whh
      for (int kc=0; kc<16; ++kc){
        short8 a[4], b[2];
        #pragma unroll
        for (int mi=0;mi<4;++mi)
          a[mi] = *(const short8*)&hs[mi*16 + l15][(kc*32 + q*8) ^ xr];
        #pragma unroll
        for (int ni=0;ni<2;++ni) b[ni] = *(const short8*)(bp2[ni] + kc*32);
        #pragma unroll
        for (int mi=0;mi<4;++mi)
          #pragma unroll
          for (int ni=0;ni<2;++ni)
            acc[mi][ni] = __builtin_amdgcn_mfma_f32_16x16x32_bf16(a[mi], b[ni], acc[mi][ni], 0,0,0);
      }
    }

    // hs reads done; zb overlays hs -> barrier before overwrite.
    __syncthreads();

    // C/D layout (m89-verified): row = q*4+r, col = l15; swizzled store (2-way max)
    #pragma unroll
    for (int mi=0;mi<4;++mi)
      #pragma unroll
      for (int ni=0;ni<2;++ni)
        #pragma unroll
        for (int r=0;r<4;++r){
          int m = mi*16 + q*4 + r;
          int col = (ni*16 + l15 + q*8) & 31;
          zb[w][m][col] = acc[mi][ni][r] + bv[ni];
        }
    __syncthreads();

    // Epilogue: thread handles (m, j2) and (m, j2+1) -> packed dword h store.
    #pragma unroll
    for (int i=0;i<4;++i){
      int pIdx = tid + 256*i;                 // 0..1023
      int m = pIdx >> 4, j2 = (pIdx & 15) << 1;
      int off = ((m>>2)&3) << 3;
      int cs0 = (j2 + off) & 31, cs1 = (j2 + 1 + off) & 31;
      float zi0 = zb[0][m][cs0], zf0 = zb[1][m][cs0], zg0 = zb[2][m][cs0], zo0 = zb[3][m][cs0];
      float zi1 = zb[0][m][cs1], zf1 = zb[1][m][cs1], zg1 = zb[2][m][cs1], zo1 = zb[3][m][cs1];
      float cn0 = sigm(zf0)*cc[2*i]   + sigm(zi0)*tanhf(zg0);
      float cn1 = sigm(zf1)*cc[2*i+1] + sigm(zi1)*tanhf(zg1);
      float hn0 = sigm(zo0)*tanhf(cn0);
      float hn1 = sigm(zo1)*tanhf(cn1);
      cc[2*i]   = cn0;
      cc[2*i+1] = cn1;
      unsigned pack = (unsigned)f2bf(hn0) | ((unsigned)f2bf(hn1) << 16);
      __hip_atomic_store((unsigned*)(h_out + (size_t)(m0+m)*Hh + j0 + j2), pack,
                         __ATOMIC_RELAXED, __HIP_MEMORY_SCOPE_AGENT);
    }

    // Release step t: drain own write-through stores, converge, tid0 counts.
    asm volatile("s_waitcnt vmcnt(0)" ::: "memory");
    __syncthreads();
    if (tid == 0)
      __hip_atomic_fetch_add(cgp, 1u, __ATOMIC_RELAXED, __HIP_MEMORY_SCOPE_AGENT);
  }

  // Final c to global (plain stores; dispatch boundary publishes to out_kernel).
  #pragma unroll
  for (int i=0;i<4;++i){
    int pIdx = tid + 256*i;
    int m = pIdx >> 4, j2 = (pIdx & 15) << 1;
    float2 cv; cv.x = cc[2*i]; cv.y = cc[2*i+1];
    *(float2*)&P.c[(size_t)(m0+m)*Hh + j0 + j2] = cv;
  }
}

// Output kernel, parallel rewrite. 256 blocks: (b, kind, u-half). v-row in LDS,
// hm via shfl-reduce (1 barrier), u-dot with 4 independent accumulators.
__global__ __launch_bounds__(256) void out_kernel(
    const unsigned short* hsc, const unsigned short* hcm, const unsigned short* his,
    const float* csc, const float* ccm, const float* cis,
    const float* Wmh, const float* bmh, const float* Wmc, const float* bmc,
    const float* Wfh, const float* bfh, const float* Wfc, const float* bfc,
    float* out)
{
  const int b    = blockIdx.x >> 2;
  const int kind = (blockIdx.x >> 1) & 1;
  const int half = blockIdx.x & 1;
  const int tid  = threadIdx.x;
  const int w = tid >> 6, lane = tid & 63;
  const float* Wm = kind ? Wmc : Wmh;
  const float* bm = kind ? bmc : bmh;
  const float* Wf = kind ? Wfc : Wfh;
  const float* bf = kind ? bfc : bfh;

  __shared__ float vis[512];
  __shared__ float wred[10][4];
  __shared__ float hmb[10];

  for (int k = tid; k < 512; k += 256)
    vis[k] = kind ? cis[(size_t)b*512 + k] : bf2f(his[(size_t)b*512 + k]);

  float pn[10];
  #pragma unroll
  for (int nc=0; nc<10; ++nc){
    size_t n = (size_t)b*10 + nc;
    float a = 0.f;
    #pragma unroll
    for (int kk=0; kk<2; ++kk){
      int k = tid + kk*256;
      float v1 = kind ? csc[n*512+k] : bf2f(hsc[n*512+k]);
      float v2 = kind ? ccm[n*512+k] : bf2f(hcm[n*512+k]);
      a += Wm[k]*v1 + Wm[512+k]*v2;
    }
    pn[nc] = a;
  }
  #pragma unroll
  for (int nc=0; nc<10; ++nc){
    float v = pn[nc];
    #pragma unroll
    for (int off=32; off; off>>=1) v += __shfl_down(v, off);
    if (lane == 0) wred[nc][w] = v;
  }
  __syncthreads();
  if (tid < 10) hmb[tid] = wred[tid][0] + wred[tid][1] + wred[tid][2] + wred[tid][3] + bm[0];
  __syncthreads();

  const int u = tid + 256*half;
  const float* wr = Wf + (size_t)u*522;
  float a0 = bf[u], a1 = 0.f, a2 = 0.f, a3 = 0.f;
  #pragma unroll
  for (int k=0; k<10; ++k) a0 += wr[k]*hmb[k];
  #pragma unroll 4
  for (int k=0; k<512; k+=4){
    a0 += wr[10+k] * vis[k];
    a1 += wr[11+k] * vis[k+1];
    a2 += wr[12+k] * vis[k+2];
    a3 += wr[13+k] * vis[k+3];
  }
  out[(size_t)kind*32768 + (size_t)b*512 + u] = (a0+a1) + (a2+a3);
}

extern "C" void kernel_launch(void* const* d_in, const int* in_sizes, int n_in,
                              void* d_out, int out_size, void* d_ws, size_t ws_size,
                              hipStream_t stream) {
  const int* comments = (const int*)d_in[0];
  const int* cm_ids   = (const int*)d_in[1];
  const int* issue    = (const int*)d_in[2];
  const float* emb_sc = (const float*)d_in[3];
  const float* emb_cm = (const float*)d_in[4];
  const float* emb_is = (const float*)d_in[5];
  const float* Wih_sc = (const float*)d_in[6];
  const float* Whh_sc = (const float*)d_in[7];
  const float* b_sc   = (const float*)d_in[8];
  const float* Wih_cm = (const float*)d_in[9];
  const float* Whh_cm = (const float*)d_in[10];
  const float* b_cm   = (const float*)d_in[11];
  const float* Wih_is = (const float*)d_in[12];
  const float* Whh_is = (const float*)d_in[13];
  const float* b_is   = (const float*)d_in[14];
  const float* Wmh = (const float*)d_in[15];
  const float* bmh = (const float*)d_in[16];
  const float* Wmc = (const float*)d_in[17];
  const float* bmc = (const float*)d_in[18];
  const float* Wfh = (const float*)d_in[19];
  const float* bfh = (const float*)d_in[20];
  const float* Wfc = (const float*)d_in[21];
  const float* bfc = (const float*)d_in[22];

  // Workspace (14.94 MB total == R3's proven extent; layout unchanged)
  char* p = (char*)d_ws;
  unsigned short* hb_sc = (unsigned short*)p; p += (size_t)2*640*512*2;
  unsigned short* hb_cm = (unsigned short*)p; p += (size_t)2*640*512*2;
  unsigned short* hb_is = (unsigned short*)p; p += (size_t)2*64*512*2;
  float* c_sc = (float*)p; p += (size_t)640*512*4;
  float* c_cm = (float*)p; p += (size_t)640*512*4;
  float* c_is = (float*)p; p += (size_t)64*512*4;
  size_t zero_bytes = (size_t)(p - (char*)d_ws);
  unsigned short* Wih_sc_b = (unsigned short*)p; p += (size_t)2048*256*2;
  unsigned short* Whh_sc_b = (unsigned short*)p; p += (size_t)2048*512*2;
  unsigned short* Wih_cm_b = (unsigned short*)p; p += (size_t)2048*256*2;
  unsigned short* Whh_cm_b = (unsigned short*)p; p += (size_t)2048*512*2;
  unsigned short* Wih_is_b = (unsigned short*)p; p += (size_t)2048*256*2;
  unsigned short* Whh_is_b = (unsigned short*)p; p += (size_t)2048*512*2;

  int n4 = (int)(zero_bytes/16);
  zero_ws_kernel<<<(n4+255)/256, 256, 0, stream>>>((uint4*)d_ws, n4);
  zero_cnt_kernel<<<1, 256, 0, stream>>>();

  const int nih8 = 2048*256/8, nhh8 = 2048*512/8;
  cvt_kernel<<<(nih8+255)/256, 256, 0, stream>>>(Wih_sc, Wih_sc_b, nih8);
  cvt_kernel<<<(nhh8+255)/256, 256, 0, stream>>>(Whh_sc, Whh_sc_b, nhh8);
  cvt_kernel<<<(nih8+255)/256, 256, 0, stream>>>(Wih_cm, Wih_cm_b, nih8);
  cvt_kernel<<<(nhh8+255)/256, 256, 0, stream>>>(Whh_cm, Whh_cm_b, nhh8);
  cvt_kernel<<<(nih8+255)/256, 256, 0, stream>>>(Wih_is, Wih_is_b, nih8);
  cvt_kernel<<<(nhh8+255)/256, 256, 0, stream>>>(Whh_is, Whh_is_b, nhh8);

  LstmP Psc = { comments, emb_sc, Wih_sc_b, Whh_sc_b, b_sc, hb_sc, c_sc, 128, 640*512 };
  LstmP Pcm = { cm_ids,   emb_cm, Wih_cm_b, Whh_cm_b, b_cm, hb_cm, c_cm,  64, 640*512 };
  LstmP Pis = { issue,    emb_is, Wih_is_b, Whh_is_b, b_is, hb_is, c_is,  32,  64*512 };
  lstm_persist<<<336, 256, 0, stream>>>(Psc, Pcm, Pis);

  // Final h states in buffer 0 for all three (T even for sc/cm/is).
  out_kernel<<<256, 256, 0, stream>>>(hb_sc, hb_cm, hb_is, c_sc, c_cm, c_is,
                                      Wmh, bmh, Wmc, bmc, Wfh, bfh, Wfc, bfc,
                                      (float*)d_out);
}

// Round 5
// 4227.720 us; speedup vs baseline: 2.3868x; 1.1196x over previous
//
#include <hip/hip_runtime.h>
#include <math.h>

#define E 256
#define Hh 512

typedef __attribute__((ext_vector_type(8))) short short8;
typedef __attribute__((ext_vector_type(4))) float f32x4;

// R17: jtile 64 (groups of 8, grid 168) + 8-byte coherent h exchange.
// R16 measured FETCH 1.03 GB = the h staging duplication (16 blocks/group
// re-reading the same slab in 4B coherent granules). Halve duplication
// (8 blocks/group), double per-block MFMA (acc[4][4]), and move all
// coherent traffic to dwordx2 (ull atomics). hs(64K)+zb(64K)=128KB LDS,
// 1 block/CU, 168<=256 co-resident. Protocol/swizzles carried from R16
// (qword swizzle algebraically identical to R16's proven 16B-chunk XOR).

struct LstmP {
  const int* ids;
  const float* emb;            // f32 embedding table (cvt to bf16 in-kernel)
  const unsigned short* Wih;   // bf16 ws cache [2048,256]
  const unsigned short* Whh;   // bf16 ws cache [2048,512]
  const float* bias;           // f32 [2048]
  unsigned short* h0;          // bf16 double buffer base (2 * nh)
  float* c;                    // f32 [N,512] final-c output
  int T;
  int nh;                      // N*512
};

__device__ unsigned g_cnt[21*32];   // per-group step counters, 128B apart

__device__ __forceinline__ float bf2f(unsigned short x){
  union { unsigned u; float f; } v; v.u = ((unsigned)x) << 16; return v.f;
}
__device__ __forceinline__ unsigned short f2bf(float f){
  union { float f; unsigned u; } v; v.f = f;
  unsigned u = v.u;
  return (unsigned short)((u + 0x7fffu + ((u >> 16) & 1u)) >> 16);
}
__device__ __forceinline__ short8 cvt8(const float* p){
  f32x4 x = *(const f32x4*)p;
  f32x4 y = *(const f32x4*)(p + 4);
  short8 r;
  r[0]=(short)f2bf(x[0]); r[1]=(short)f2bf(x[1]); r[2]=(short)f2bf(x[2]); r[3]=(short)f2bf(x[3]);
  r[4]=(short)f2bf(y[0]); r[5]=(short)f2bf(y[1]); r[6]=(short)f2bf(y[2]); r[7]=(short)f2bf(y[3]);
  return r;
}
__device__ __forceinline__ float sigm(float x){ return 1.0f/(1.0f + expf(-x)); }

__global__ void zero_ws_kernel(uint4* p, int n){
  int i = blockIdx.x*256 + threadIdx.x;
  if (i < n){ uint4 z; z.x=0u; z.y=0u; z.z=0u; z.w=0u; p[i]=z; }
}

__global__ void zero_cnt_kernel(){
  for (int i = threadIdx.x; i < 21*32; i += 256) g_cnt[i] = 0u;
}

// f32 -> bf16 (RNE), 8 elems/thread. (R3-proven cache bit-match.)
__global__ __launch_bounds__(256) void cvt_kernel(const float* src, unsigned short* dst, int n8){
  int i = blockIdx.x*256 + threadIdx.x;
  if (i < n8){
    *(short8*)(dst + (size_t)i*8) = cvt8(src + (size_t)i*8);
  }
}

// Persistent kernel: block = one (lstm, mb, jt64) tile for all T steps.
// Per step: phase1 (emb x Wih) -> group wait -> coherent qword h stage to LDS
// -> phase2 (h x Whh from LDS) -> zb exchange -> epilogue (c in regs, packed
// qword coherent h store) -> vmcnt drain -> barrier -> release.
__global__ __launch_bounds__(256) void lstm_persist(LstmP sc, LstmP cm, LstmP is_)
{
  __shared__ unsigned short hs[64][512];   // 64 KB staged h slab (swizzled)
  __shared__ float zb[4][64][64];          // 64 KB gate exchange

  LstmP P; int tile, grp;
  {
    int idx = blockIdx.x;
    if (idx < 80){ P = sc;  tile = idx;        grp = tile >> 3; }
    else if (idx < 160){ P = cm;  tile = idx - 80;   grp = 10 + (tile >> 3); }
    else { P = is_; tile = idx - 160;  grp = 20; }
  }
  const int tid  = threadIdx.x;
  const int w    = tid >> 6;       // gate 0..3 = i,f,g,o
  const int lane = tid & 63;
  const int l15  = lane & 15;
  const int q    = lane >> 4;
  const int mb = tile >> 3, jt = tile & 7;
  const int m0 = mb*64, j0 = jt*64;
  const int T = P.T;
  unsigned* cgp = &g_cnt[grp*32];
  const int xr = (l15 & 7) << 3;   // hs row-XOR swizzle (per-lane const, in shorts)

  const int* idrow[4];             // ids row per A-fragment row
  #pragma unroll
  for (int mi=0; mi<4; ++mi){
    int m = m0 + mi*16 + l15;
    idrow[mi] = P.ids + (size_t)m*T;
  }
  const unsigned short* bp1[4];    // bf16 Wih rows (B row = gate unit = l15)
  const unsigned short* bp2[4];
  float bv[4];
  #pragma unroll
  for (int ni=0; ni<4; ++ni){
    int n = w*Hh + j0 + ni*16 + l15;
    bp1[ni] = P.Wih + (size_t)n*E  + q*8;
    bp2[ni] = P.Whh + (size_t)n*Hh + q*8;
    bv[ni]  = P.bias[n];
  }

  float cc[16];                    // persistent cell state (epilogue-mapped)
  #pragma unroll
  for (int i=0;i<16;++i) cc[i] = 0.f;

  for (int t = 0; t < T; ++t){
    const unsigned short* h_in  = P.h0 + (size_t)(t&1)*P.nh;
    unsigned short*       h_out = P.h0 + (size_t)((t+1)&1)*P.nh;

    f32x4 acc[4][4];
    #pragma unroll
    for (int i=0;i<4;++i)
      #pragma unroll
      for (int j=0;j<4;++j) acc[i][j] = (f32x4){0.f,0.f,0.f,0.f};

    // Phase 1: K=0..255, x = emb (cvt f32->bf16), W = Wih. No h dependence:
    // runs BEFORE the group wait to hide sync latency.
    const float* ap1[4];
    #pragma unroll
    for (int mi=0; mi<4; ++mi){
      int id = idrow[mi][t];
      ap1[mi] = P.emb + (size_t)id*E + q*8;
    }
    for (int kc=0; kc<8; ++kc){
      short8 a[4], b[4];
      #pragma unroll
      for (int mi=0;mi<4;++mi) a[mi] = cvt8(ap1[mi] + kc*32);
      #pragma unroll
      for (int ni=0;ni<4;++ni) b[ni] = *(const short8*)(bp1[ni] + kc*32);
      #pragma unroll
      for (int mi=0;mi<4;++mi)
        #pragma unroll
        for (int ni=0;ni<4;++ni)
          acc[mi][ni] = __builtin_amdgcn_mfma_f32_16x16x32_bf16(a[mi], b[ni], acc[mi][ni], 0,0,0);
    }

    // Wait for h(t): all 8 group blocks released step t-1 => counter >= 8*t.
    // t==0: h is all zeros -> phase 2 contributes exact zeros, skip it.
    if (t > 0){
      if (tid == 0){
        unsigned tgt = 8u * (unsigned)t;
        long guard = 0;
        while (__hip_atomic_load(cgp, __ATOMIC_RELAXED, __HIP_MEMORY_SCOPE_AGENT) < tgt){
          __builtin_amdgcn_s_sleep(1);
          if (++guard > 2000000L) break;   // convert protocol bug -> wrong answer, not hang
        }
      }
      __syncthreads();
      asm volatile("" ::: "memory");       // compiler-only fence (no cache ops)

      // Stage h rows m0..m0+63 into LDS via device-coherent qword loads.
      // Swizzle in qword units: dst_short = 4*qp ^ ((row&7)<<3) -- identical
      // 16B-chunk permutation to R16's proven dword form.
      {
        const unsigned long long* src = (const unsigned long long*)(h_in + (size_t)m0*Hh);
        #pragma unroll 8
        for (int d = tid; d < 64*128; d += 256){
          unsigned long long v = __hip_atomic_load(src + d, __ATOMIC_RELAXED, __HIP_MEMORY_SCOPE_AGENT);
          int row = d >> 7, qp = d & 127;
          *(unsigned long long*)&hs[row][(qp ^ ((row & 7) << 1)) << 2] = v;
        }
      }
      __syncthreads();

      // Phase 2: K=256..767, x = h (bf16, from swizzled LDS), W = Whh
      for (int kc=0; kc<16; ++kc){
        short8 a[4], b[4];
        #pragma unroll
        for (int mi=0;mi<4;++mi)
          a[mi] = *(const short8*)&hs[mi*16 + l15][(kc*32 + q*8) ^ xr];
        #pragma unroll
        for (int ni=0;ni<4;++ni) b[ni] = *(const short8*)(bp2[ni] + kc*32);
        #pragma unroll
        for (int mi=0;mi<4;++mi)
          #pragma unroll
          for (int ni=0;ni<4;++ni)
            acc[mi][ni] = __builtin_amdgcn_mfma_f32_16x16x32_bf16(a[mi], b[ni], acc[mi][ni], 0,0,0);
      }
    }

    // C/D layout (m89-verified): row = q*4+r, col = l15; swizzled store.
    // col = (j + 8q) & 63 is bijective per (q); <=2-way banks (same as R12 &31 form).
    #pragma unroll
    for (int mi=0;mi<4;++mi)
      #pragma unroll
      for (int ni=0;ni<4;++ni)
        #pragma unroll
        for (int r=0;r<4;++r){
          int m = mi*16 + q*4 + r;
          int col = (ni*16 + l15 + q*8) & 63;
          zb[w][m][col] = acc[mi][ni][r] + bv[ni];
        }
    __syncthreads();

    // Epilogue: thread handles (m, j4..j4+3) -> f32x4 zb reads, packed qword h store.
    #pragma unroll
    for (int i=0;i<4;++i){
      int pIdx = tid + 256*i;                 // 0..1023 over 64 rows x 16 quads
      int m = pIdx >> 4, j4 = (pIdx & 15) << 2;
      int cs = (j4 + (((m>>2)&3) << 3)) & 63; // inverse swizzle, quad-aligned (no wrap in quad)
      f32x4 zi = *(const f32x4*)&zb[0][m][cs];
      f32x4 zf = *(const f32x4*)&zb[1][m][cs];
      f32x4 zg = *(const f32x4*)&zb[2][m][cs];
      f32x4 zo = *(const f32x4*)&zb[3][m][cs];
      unsigned long long pack = 0ull;
      #pragma unroll
      for (int k=0;k<4;++k){
        float cn = sigm(zf[k])*cc[i*4+k] + sigm(zi[k])*tanhf(zg[k]);
        float hn = sigm(zo[k])*tanhf(cn);
        cc[i*4+k] = cn;
        pack |= ((unsigned long long)f2bf(hn)) << (16*k);
      }
      __hip_atomic_store((unsigned long long*)(h_out + (size_t)(m0+m)*Hh + j0 + j4), pack,
                         __ATOMIC_RELAXED, __HIP_MEMORY_SCOPE_AGENT);
    }

    // Release step t: drain own write-through stores, converge, tid0 counts.
    asm volatile("s_waitcnt vmcnt(0)" ::: "memory");
    __syncthreads();
    if (tid == 0)
      __hip_atomic_fetch_add(cgp, 1u, __ATOMIC_RELAXED, __HIP_MEMORY_SCOPE_AGENT);
  }

  // Final c to global (plain stores; dispatch boundary publishes to out_kernel).
  #pragma unroll
  for (int i=0;i<4;++i){
    int pIdx = tid + 256*i;
    int m = pIdx >> 4, j4 = (pIdx & 15) << 2;
    f32x4 cv; cv[0]=cc[i*4]; cv[1]=cc[i*4+1]; cv[2]=cc[i*4+2]; cv[3]=cc[i*4+3];
    *(f32x4*)&P.c[(size_t)(m0+m)*Hh + j0 + j4] = cv;
  }
}

// Output kernel (R16-proven). 256 blocks: (b, kind, u-half). v-row in LDS,
// hm via shfl-reduce (1 barrier), u-dot with 4 independent accumulators.
__global__ __launch_bounds__(256) void out_kernel(
    const unsigned short* hsc, const unsigned short* hcm, const unsigned short* his,
    const float* csc, const float* ccm, const float* cis,
    const float* Wmh, const float* bmh, const float* Wmc, const float* bmc,
    const float* Wfh, const float* bfh, const float* Wfc, const float* bfc,
    float* out)
{
  const int b    = blockIdx.x >> 2;
  const int kind = (blockIdx.x >> 1) & 1;
  const int half = blockIdx.x & 1;
  const int tid  = threadIdx.x;
  const int w = tid >> 6, lane = tid & 63;
  const float* Wm = kind ? Wmc : Wmh;
  const float* bm = kind ? bmc : bmh;
  const float* Wf = kind ? Wfc : Wfh;
  const float* bf = kind ? bfc : bfh;

  __shared__ float vis[512];
  __shared__ float wred[10][4];
  __shared__ float hmb[10];

  for (int k = tid; k < 512; k += 256)
    vis[k] = kind ? cis[(size_t)b*512 + k] : bf2f(his[(size_t)b*512 + k]);

  float pn[10];
  #pragma unroll
  for (int nc=0; nc<10; ++nc){
    size_t n = (size_t)b*10 + nc;
    float a = 0.f;
    #pragma unroll
    for (int kk=0; kk<2; ++kk){
      int k = tid + kk*256;
      float v1 = kind ? csc[n*512+k] : bf2f(hsc[n*512+k]);
      float v2 = kind ? ccm[n*512+k] : bf2f(hcm[n*512+k]);
      a += Wm[k]*v1 + Wm[512+k]*v2;
    }
    pn[nc] = a;
  }
  #pragma unroll
  for (int nc=0; nc<10; ++nc){
    float v = pn[nc];
    #pragma unroll
    for (int off=32; off; off>>=1) v += __shfl_down(v, off);
    if (lane == 0) wred[nc][w] = v;
  }
  __syncthreads();
  if (tid < 10) hmb[tid] = wred[tid][0] + wred[tid][1] + wred[tid][2] + wred[tid][3] + bm[0];
  __syncthreads();

  const int u = tid + 256*half;
  const float* wr = Wf + (size_t)u*522;
  float a0 = bf[u], a1 = 0.f, a2 = 0.f, a3 = 0.f;
  #pragma unroll
  for (int k=0; k<10; ++k) a0 += wr[k]*hmb[k];
  #pragma unroll 4
  for (int k=0; k<512; k+=4){
    a0 += wr[10+k] * vis[k];
    a1 += wr[11+k] * vis[k+1];
    a2 += wr[12+k] * vis[k+2];
    a3 += wr[13+k] * vis[k+3];
  }
  out[(size_t)kind*32768 + (size_t)b*512 + u] = (a0+a1) + (a2+a3);
}

extern "C" void kernel_launch(void* const* d_in, const int* in_sizes, int n_in,
                              void* d_out, int out_size, void* d_ws, size_t ws_size,
                              hipStream_t stream) {
  const int* comments = (const int*)d_in[0];
  const int* cm_ids   = (const int*)d_in[1];
  const int* issue    = (const int*)d_in[2];
  const float* emb_sc = (const float*)d_in[3];
  const float* emb_cm = (const float*)d_in[4];
  const float* emb_is = (const float*)d_in[5];
  const float* Wih_sc = (const float*)d_in[6];
  const float* Whh_sc = (const float*)d_in[7];
  const float* b_sc   = (const float*)d_in[8];
  const float* Wih_cm = (const float*)d_in[9];
  const float* Whh_cm = (const float*)d_in[10];
  const float* b_cm   = (const float*)d_in[11];
  const float* Wih_is = (const float*)d_in[12];
  const float* Whh_is = (const float*)d_in[13];
  const float* b_is   = (const float*)d_in[14];
  const float* Wmh = (const float*)d_in[15];
  const float* bmh = (const float*)d_in[16];
  const float* Wmc = (const float*)d_in[17];
  const float* bmc = (const float*)d_in[18];
  const float* Wfh = (const float*)d_in[19];
  const float* bfh = (const float*)d_in[20];
  const float* Wfc = (const float*)d_in[21];
  const float* bfc = (const float*)d_in[22];

  // Workspace (14.94 MB total == R3's proven extent; layout unchanged)
  char* p = (char*)d_ws;
  unsigned short* hb_sc = (unsigned short*)p; p += (size_t)2*640*512*2;
  unsigned short* hb_cm = (unsigned short*)p; p += (size_t)2*640*512*2;
  unsigned short* hb_is = (unsigned short*)p; p += (size_t)2*64*512*2;
  float* c_sc = (float*)p; p += (size_t)640*512*4;
  float* c_cm = (float*)p; p += (size_t)640*512*4;
  float* c_is = (float*)p; p += (size_t)64*512*4;
  size_t zero_bytes = (size_t)(p - (char*)d_ws);
  unsigned short* Wih_sc_b = (unsigned short*)p; p += (size_t)2048*256*2;
  unsigned short* Whh_sc_b = (unsigned short*)p; p += (size_t)2048*512*2;
  unsigned short* Wih_cm_b = (unsigned short*)p; p += (size_t)2048*256*2;
  unsigned short* Whh_cm_b = (unsigned short*)p; p += (size_t)2048*512*2;
  unsigned short* Wih_is_b = (unsigned short*)p; p += (size_t)2048*256*2;
  unsigned short* Whh_is_b = (unsigned short*)p; p += (size_t)2048*512*2;

  int n4 = (int)(zero_bytes/16);
  zero_ws_kernel<<<(n4+255)/256, 256, 0, stream>>>((uint4*)d_ws, n4);
  zero_cnt_kernel<<<1, 256, 0, stream>>>();

  const int nih8 = 2048*256/8, nhh8 = 2048*512/8;
  cvt_kernel<<<(nih8+255)/256, 256, 0, stream>>>(Wih_sc, Wih_sc_b, nih8);
  cvt_kernel<<<(nhh8+255)/256, 256, 0, stream>>>(Whh_sc, Whh_sc_b, nhh8);
  cvt_kernel<<<(nih8+255)/256, 256, 0, stream>>>(Wih_cm, Wih_cm_b, nih8);
  cvt_kernel<<<(nhh8+255)/256, 256, 0, stream>>>(Whh_cm, Whh_cm_b, nhh8);
  cvt_kernel<<<(nih8+255)/256, 256, 0, stream>>>(Wih_is, Wih_is_b, nih8);
  cvt_kernel<<<(nhh8+255)/256, 256, 0, stream>>>(Whh_is, Whh_is_b, nhh8);

  LstmP Psc = { comments, emb_sc, Wih_sc_b, Whh_sc_b, b_sc, hb_sc, c_sc, 128, 640*512 };
  LstmP Pcm = { cm_ids,   emb_cm, Wih_cm_b, Whh_cm_b, b_cm, hb_cm, c_cm,  64, 640*512 };
  LstmP Pis = { issue,    emb_is, Wih_is_b, Whh_is_b, b_is, hb_is, c_is,  32,  64*512 };
  lstm_persist<<<168, 256, 0, stream>>>(Psc, Pcm, Pis);

  // Final h states in buffer 0 for all three (T even for sc/cm/is).
  out_kernel<<<256, 256, 0, stream>>>(hb_sc, hb_cm, hb_is, c_sc, c_cm, c_is,
                                      Wmh, bmh, Wmc, bmc, Wfh, bfh, Wfc, bfc,
                                      (float*)d_out);
}

// Round 6
// 3445.613 us; speedup vs baseline: 2.9286x; 1.2270x over previous
//
#include <hip/hip_runtime.h>
#include <math.h>

#define E 256
#define Hh 512

typedef __attribute__((ext_vector_type(8))) short short8;
typedef __attribute__((ext_vector_type(4))) float f32x4;

// R18: gate-per-lane restructure. Wave w owns j-slice [j0+16w, j0+16w+16) for
// ALL 4 gates (B-fragments indexed by gate) -> i,f,g,o for each (m,j) land in
// one lane's 4 accs -> LSTM pointwise epilogue fully in registers. The 32KB
// zb gate-exchange LDS (23.8M bank-conflict cycles in R17) is deleted; only a
// 4KB h-shuttle packs bf16 quads for the proven qword coherent stores.
// M=32 tiles -> 336 blocks (groups of 8 unchanged), LDS 36KB -> 3-4 blocks/CU
// for latency overlap. Fast sigm/tanh via v_exp/v_rcp. Sync protocol, staging
// swizzle, and coherent-atomic h exchange carried verbatim from R17 (proven).

struct LstmP {
  const int* ids;
  const float* emb;            // f32 embedding table (cvt to bf16 in-kernel)
  const unsigned short* Wih;   // bf16 ws cache [2048,256]
  const unsigned short* Whh;   // bf16 ws cache [2048,512]
  const float* bias;           // f32 [2048]
  unsigned short* h0;          // bf16 double buffer base (2 * nh)
  float* c;                    // f32 [N,512] final-c output
  int T;
  int nh;                      // N*512
};

__device__ unsigned g_cnt[42*32];   // per-group step counters, 128B apart

__device__ __forceinline__ float bf2f(unsigned short x){
  union { unsigned u; float f; } v; v.u = ((unsigned)x) << 16; return v.f;
}
__device__ __forceinline__ unsigned short f2bf(float f){
  union { float f; unsigned u; } v; v.f = f;
  unsigned u = v.u;
  return (unsigned short)((u + 0x7fffu + ((u >> 16) & 1u)) >> 16);
}
__device__ __forceinline__ short8 cvt8(const float* p){
  f32x4 x = *(const f32x4*)p;
  f32x4 y = *(const f32x4*)(p + 4);
  short8 r;
  r[0]=(short)f2bf(x[0]); r[1]=(short)f2bf(x[1]); r[2]=(short)f2bf(x[2]); r[3]=(short)f2bf(x[3]);
  r[4]=(short)f2bf(y[0]); r[5]=(short)f2bf(y[1]); r[6]=(short)f2bf(y[2]); r[7]=(short)f2bf(y[3]);
  return r;
}
// Fast activations: v_exp_f32 computes 2^x; v_rcp_f32 ~1ulp. Per-step rel err
// ~1e-7, compounding over 128 steps ~1e-5 -- far under the 1.6e-4 threshold.
__device__ __forceinline__ float sigm(float x){
  return __builtin_amdgcn_rcpf(1.0f + __builtin_amdgcn_exp2f(-1.44269504f*x));
}
__device__ __forceinline__ float tanh_f(float x){
  return 1.0f - 2.0f*__builtin_amdgcn_rcpf(1.0f + __builtin_amdgcn_exp2f(2.88539008f*x));
}

__global__ void zero_ws_kernel(uint4* p, int n){
  int i = blockIdx.x*256 + threadIdx.x;
  if (i < n){ uint4 z; z.x=0u; z.y=0u; z.z=0u; z.w=0u; p[i]=z; }
}

__global__ void zero_cnt_kernel(){
  for (int i = threadIdx.x; i < 42*32; i += 256) g_cnt[i] = 0u;
}

// f32 -> bf16 (RNE), 8 elems/thread. (R3-proven cache bit-match.)
__global__ __launch_bounds__(256) void cvt_kernel(const float* src, unsigned short* dst, int n8){
  int i = blockIdx.x*256 + threadIdx.x;
  if (i < n8){
    *(short8*)(dst + (size_t)i*8) = cvt8(src + (size_t)i*8);
  }
}

// Persistent kernel: block = one (lstm, mb32, jt64) tile for all T steps.
// Per step: phase1 (emb x Wih, 4 gate-fragments) -> group wait -> coherent
// qword h stage to LDS -> phase2 (h x Whh) -> in-register epilogue ->
// 4KB shuttle pack -> qword coherent h store -> drain -> barrier -> release.
__global__ __launch_bounds__(256, 2) void lstm_persist(LstmP sc, LstmP cm, LstmP is_)
{
  __shared__ unsigned short hs[32][512];   // 32 KB staged h slab (swizzled)
  __shared__ unsigned short sh_h[32][64];  // 4 KB h shuttle (pack for qword stores)

  LstmP P; int tile, grp;
  {
    int idx = blockIdx.x;
    if (idx < 160){ P = sc;  tile = idx;        grp = tile >> 3; }
    else if (idx < 320){ P = cm;  tile = idx - 160;  grp = 20 + (tile >> 3); }
    else { P = is_; tile = idx - 320;  grp = 40 + (tile >> 3); }
  }
  const int tid  = threadIdx.x;
  const int w    = tid >> 6;       // wave = j-subslice owner (all 4 gates)
  const int lane = tid & 63;
  const int l15  = lane & 15;
  const int q    = lane >> 4;
  const int mb = tile >> 3, jt = tile & 7;
  const int m0 = mb*32, j0 = jt*64;
  const int jw = j0 + w*16;
  const int T = P.T;
  unsigned* cgp = &g_cnt[grp*32];
  const int xr = (l15 & 7) << 3;   // hs row-XOR swizzle (per-lane const, in shorts)

  const int* idrow[2];             // ids row per A-fragment row
  #pragma unroll
  for (int mi=0; mi<2; ++mi){
    int m = m0 + mi*16 + l15;
    idrow[mi] = P.ids + (size_t)m*T;
  }
  const unsigned short* bg1[4];    // bf16 Wih rows: gate g, unit jw+l15
  const unsigned short* bg2[4];
  float bvv[4];
  #pragma unroll
  for (int g=0; g<4; ++g){
    int n = g*Hh + jw + l15;
    bg1[g] = P.Wih + (size_t)n*E  + q*8;
    bg2[g] = P.Whh + (size_t)n*Hh + q*8;
    bvv[g] = P.bias[n];
  }

  float cc[8];                     // persistent cell state: (mi,r) -> row mi*16+q*4+r, col jw+l15
  #pragma unroll
  for (int i=0;i<8;++i) cc[i] = 0.f;

  for (int t = 0; t < T; ++t){
    const unsigned short* h_in  = P.h0 + (size_t)(t&1)*P.nh;
    unsigned short*       h_out = P.h0 + (size_t)((t+1)&1)*P.nh;

    f32x4 acc[2][4];
    #pragma unroll
    for (int i=0;i<2;++i)
      #pragma unroll
      for (int g=0;g<4;++g) acc[i][g] = (f32x4){0.f,0.f,0.f,0.f};

    // Phase 1: K=0..255, x = emb (cvt f32->bf16), W = Wih. No h dependence:
    // runs BEFORE the group wait to hide sync latency.
    const float* ap1[2];
    #pragma unroll
    for (int mi=0; mi<2; ++mi){
      int id = idrow[mi][t];
      ap1[mi] = P.emb + (size_t)id*E + q*8;
    }
    #pragma unroll 2
    for (int kc=0; kc<8; ++kc){
      short8 a[2], b[4];
      #pragma unroll
      for (int mi=0;mi<2;++mi) a[mi] = cvt8(ap1[mi] + kc*32);
      #pragma unroll
      for (int g=0;g<4;++g) b[g] = *(const short8*)(bg1[g] + kc*32);
      #pragma unroll
      for (int mi=0;mi<2;++mi)
        #pragma unroll
        for (int g=0;g<4;++g)
          acc[mi][g] = __builtin_amdgcn_mfma_f32_16x16x32_bf16(a[mi], b[g], acc[mi][g], 0,0,0);
    }

    // Wait for h(t): all 8 group blocks released step t-1 => counter >= 8*t.
    // t==0: h is all zeros -> phase 2 contributes exact zeros, skip it.
    if (t > 0){
      if (tid == 0){
        unsigned tgt = 8u * (unsigned)t;
        long guard = 0;
        while (__hip_atomic_load(cgp, __ATOMIC_RELAXED, __HIP_MEMORY_SCOPE_AGENT) < tgt){
          __builtin_amdgcn_s_sleep(1);
          if (++guard > 2000000L) break;   // convert protocol bug -> wrong answer, not hang
        }
      }
      __syncthreads();
      asm volatile("" ::: "memory");       // compiler-only fence (no cache ops)

      // Stage h rows m0..m0+31 into LDS via device-coherent qword loads
      // (R17-proven swizzle, 16 loads/thread fully unrolled -> one round trip).
      {
        const unsigned long long* src = (const unsigned long long*)(h_in + (size_t)m0*Hh);
        #pragma unroll
        for (int i=0; i<16; ++i){
          int d = tid + 256*i;
          unsigned long long v = __hip_atomic_load(src + d, __ATOMIC_RELAXED, __HIP_MEMORY_SCOPE_AGENT);
          int row = d >> 7, qp = d & 127;
          *(unsigned long long*)&hs[row][(qp ^ ((row & 7) << 1)) << 2] = v;
        }
      }
      __syncthreads();

      // Phase 2: K=256..767, x = h (bf16, from swizzled LDS), W = Whh
      #pragma unroll 2
      for (int kc=0; kc<16; ++kc){
        short8 a[2], b[4];
        #pragma unroll
        for (int mi=0;mi<2;++mi)
          a[mi] = *(const short8*)&hs[mi*16 + l15][(kc*32 + q*8) ^ xr];
        #pragma unroll
        for (int g=0;g<4;++g) b[g] = *(const short8*)(bg2[g] + kc*32);
        #pragma unroll
        for (int mi=0;mi<2;++mi)
          #pragma unroll
          for (int g=0;g<4;++g)
            acc[mi][g] = __builtin_amdgcn_mfma_f32_16x16x32_bf16(a[mi], b[g], acc[mi][g], 0,0,0);
      }
    }

    // In-register epilogue: C layout (m89-verified) row=q*4+r, col=l15 -> this
    // lane's element (mi*16+q*4+r, jw+l15) has all 4 gates in acc[mi][g][r].
    #pragma unroll
    for (int mi=0;mi<2;++mi)
      #pragma unroll
      for (int r=0;r<4;++r){
        float zi = acc[mi][0][r] + bvv[0];
        float zf = acc[mi][1][r] + bvv[1];
        float zg = acc[mi][2][r] + bvv[2];
        float zo = acc[mi][3][r] + bvv[3];
        float cn = sigm(zf)*cc[mi*4+r] + sigm(zi)*tanh_f(zg);
        float hn = sigm(zo)*tanh_f(cn);
        cc[mi*4+r] = cn;
        sh_h[mi*16 + q*4 + r][w*16 + l15] = f2bf(hn);
      }
    __syncthreads();

    // Pack shuttle -> qword coherent h stores (R17-proven store path).
    #pragma unroll
    for (int i=0;i<2;++i){
      int pIdx = tid + 256*i;                 // 0..511 = 32 rows x 16 quads
      int m = pIdx >> 4, j4 = (pIdx & 15) << 2;
      unsigned long long pk = *(const unsigned long long*)&sh_h[m][j4];
      __hip_atomic_store((unsigned long long*)(h_out + (size_t)(m0+m)*Hh + j0 + j4), pk,
                         __ATOMIC_RELAXED, __HIP_MEMORY_SCOPE_AGENT);
    }

    // Release step t: drain own write-through stores, converge, tid0 counts.
    asm volatile("s_waitcnt vmcnt(0)" ::: "memory");
    __syncthreads();
    if (tid == 0)
      __hip_atomic_fetch_add(cgp, 1u, __ATOMIC_RELAXED, __HIP_MEMORY_SCOPE_AGENT);
  }

  // Final c to global (plain stores; dispatch boundary publishes to out_kernel).
  #pragma unroll
  for (int mi=0;mi<2;++mi)
    #pragma unroll
    for (int r=0;r<4;++r)
      P.c[(size_t)(m0 + mi*16 + q*4 + r)*Hh + jw + l15] = cc[mi*4+r];
}

// Output kernel (R16-proven). 256 blocks: (b, kind, u-half). v-row in LDS,
// hm via shfl-reduce (1 barrier), u-dot with 4 independent accumulators.
__global__ __launch_bounds__(256) void out_kernel(
    const unsigned short* hsc, const unsigned short* hcm, const unsigned short* his,
    const float* csc, const float* ccm, const float* cis,
    const float* Wmh, const float* bmh, const float* Wmc, const float* bmc,
    const float* Wfh, const float* bfh, const float* Wfc, const float* bfc,
    float* out)
{
  const int b    = blockIdx.x >> 2;
  const int kind = (blockIdx.x >> 1) & 1;
  const int half = blockIdx.x & 1;
  const int tid  = threadIdx.x;
  const int w = tid >> 6, lane = tid & 63;
  const float* Wm = kind ? Wmc : Wmh;
  const float* bm = kind ? bmc : bmh;
  const float* Wf = kind ? Wfc : Wfh;
  const float* bf = kind ? bfc : bfh;

  __shared__ float vis[512];
  __shared__ float wred[10][4];
  __shared__ float hmb[10];

  for (int k = tid; k < 512; k += 256)
    vis[k] = kind ? cis[(size_t)b*512 + k] : bf2f(his[(size_t)b*512 + k]);

  float pn[10];
  #pragma unroll
  for (int nc=0; nc<10; ++nc){
    size_t n = (size_t)b*10 + nc;
    float a = 0.f;
    #pragma unroll
    for (int kk=0; kk<2; ++kk){
      int k = tid + kk*256;
      float v1 = kind ? csc[n*512+k] : bf2f(hsc[n*512+k]);
      float v2 = kind ? ccm[n*512+k] : bf2f(hcm[n*512+k]);
      a += Wm[k]*v1 + Wm[512+k]*v2;
    }
    pn[nc] = a;
  }
  #pragma unroll
  for (int nc=0; nc<10; ++nc){
    float v = pn[nc];
    #pragma unroll
    for (int off=32; off; off>>=1) v += __shfl_down(v, off);
    if (lane == 0) wred[nc][w] = v;
  }
  __syncthreads();
  if (tid < 10) hmb[tid] = wred[tid][0] + wred[tid][1] + wred[tid][2] + wred[tid][3] + bm[0];
  __syncthreads();

  const int u = tid + 256*half;
  const float* wr = Wf + (size_t)u*522;
  float a0 = bf[u], a1 = 0.f, a2 = 0.f, a3 = 0.f;
  #pragma unroll
  for (int k=0; k<10; ++k) a0 += wr[k]*hmb[k];
  #pragma unroll 4
  for (int k=0; k<512; k+=4){
    a0 += wr[10+k] * vis[k];
    a1 += wr[11+k] * vis[k+1];
    a2 += wr[12+k] * vis[k+2];
    a3 += wr[13+k] * vis[k+3];
  }
  out[(size_t)kind*32768 + (size_t)b*512 + u] = (a0+a1) + (a2+a3);
}

extern "C" void kernel_launch(void* const* d_in, const int* in_sizes, int n_in,
                              void* d_out, int out_size, void* d_ws, size_t ws_size,
                              hipStream_t stream) {
  const int* comments = (const int*)d_in[0];
  const int* cm_ids   = (const int*)d_in[1];
  const int* issue    = (const int*)d_in[2];
  const float* emb_sc = (const float*)d_in[3];
  const float* emb_cm = (const float*)d_in[4];
  const float* emb_is = (const float*)d_in[5];
  const float* Wih_sc = (const float*)d_in[6];
  const float* Whh_sc = (const float*)d_in[7];
  const float* b_sc   = (const float*)d_in[8];
  const float* Wih_cm = (const float*)d_in[9];
  const float* Whh_cm = (const float*)d_in[10];
  const float* b_cm   = (const float*)d_in[11];
  const float* Wih_is = (const float*)d_in[12];
  const float* Whh_is = (const float*)d_in[13];
  const float* b_is   = (const float*)d_in[14];
  const float* Wmh = (const float*)d_in[15];
  const float* bmh = (const float*)d_in[16];
  const float* Wmc = (const float*)d_in[17];
  const float* bmc = (const float*)d_in[18];
  const float* Wfh = (const float*)d_in[19];
  const float* bfh = (const float*)d_in[20];
  const float* Wfc = (const float*)d_in[21];
  const float* bfc = (const float*)d_in[22];

  // Workspace (14.94 MB total == R3's proven extent; layout unchanged)
  char* p = (char*)d_ws;
  unsigned short* hb_sc = (unsigned short*)p; p += (size_t)2*640*512*2;
  unsigned short* hb_cm = (unsigned short*)p; p += (size_t)2*640*512*2;
  unsigned short* hb_is = (unsigned short*)p; p += (size_t)2*64*512*2;
  float* c_sc = (float*)p; p += (size_t)640*512*4;
  float* c_cm = (float*)p; p += (size_t)640*512*4;
  float* c_is = (float*)p; p += (size_t)64*512*4;
  size_t zero_bytes = (size_t)(p - (char*)d_ws);
  unsigned short* Wih_sc_b = (unsigned short*)p; p += (size_t)2048*256*2;
  unsigned short* Whh_sc_b = (unsigned short*)p; p += (size_t)2048*512*2;
  unsigned short* Wih_cm_b = (unsigned short*)p; p += (size_t)2048*256*2;
  unsigned short* Whh_cm_b = (unsigned short*)p; p += (size_t)2048*512*2;
  unsigned short* Wih_is_b = (unsigned short*)p; p += (size_t)2048*256*2;
  unsigned short* Whh_is_b = (unsigned short*)p; p += (size_t)2048*512*2;

  int n4 = (int)(zero_bytes/16);
  zero_ws_kernel<<<(n4+255)/256, 256, 0, stream>>>((uint4*)d_ws, n4);
  zero_cnt_kernel<<<1, 256, 0, stream>>>();

  const int nih8 = 2048*256/8, nhh8 = 2048*512/8;
  cvt_kernel<<<(nih8+255)/256, 256, 0, stream>>>(Wih_sc, Wih_sc_b, nih8);
  cvt_kernel<<<(nhh8+255)/256, 256, 0, stream>>>(Whh_sc, Whh_sc_b, nhh8);
  cvt_kernel<<<(nih8+255)/256, 256, 0, stream>>>(Wih_cm, Wih_cm_b, nih8);
  cvt_kernel<<<(nhh8+255)/256, 256, 0, stream>>>(Whh_cm, Whh_cm_b, nhh8);
  cvt_kernel<<<(nih8+255)/256, 256, 0, stream>>>(Wih_is, Wih_is_b, nih8);
  cvt_kernel<<<(nhh8+255)/256, 256, 0, stream>>>(Whh_is, Whh_is_b, nhh8);

  LstmP Psc = { comments, emb_sc, Wih_sc_b, Whh_sc_b, b_sc, hb_sc, c_sc, 128, 640*512 };
  LstmP Pcm = { cm_ids,   emb_cm, Wih_cm_b, Whh_cm_b, b_cm, hb_cm, c_cm,  64, 640*512 };
  LstmP Pis = { issue,    emb_is, Wih_is_b, Whh_is_b, b_is, hb_is, c_is,  32,  64*512 };
  lstm_persist<<<336, 256, 0, stream>>>(Psc, Pcm, Pis);

  // Final h states in buffer 0 for all three (T even for sc/cm/is).
  out_kernel<<<256, 256, 0, stream>>>(hb_sc, hb_cm, hb_is, c_sc, c_cm, c_is,
                                      Wmh, bmh, Wmc, bmc, Wfh, bfh, Wfc, bfc,
                                      (float*)d_out);
}

// Round 7
// 3125.464 us; speedup vs baseline: 3.2286x; 1.1024x over previous
//
#include <hip/hip_runtime.h>
#include <math.h>

#define E 256
#define Hh 512

typedef __attribute__((ext_vector_type(8))) short short8;
typedef __attribute__((ext_vector_type(4))) float f32x4;
typedef __attribute__((ext_vector_type(4))) unsigned uint4v;

// R19: 16B coherent transactions + staging overlapped under phase-1.
// R16->R18 showed effective coherent-exchange rate scales with transaction
// width (259 -> 365 GB/s for 4B -> 8B): transaction-rate bound, not bytes.
// So: dwordx4 sc0 sc1 loads/stores (half the transactions), issued into
// registers right after the group wait and deposited to LDS after phase-1
// (latency hidden under MFMA). Swizzle re-derived in 16B units (identical
// permutation). Everything else verbatim R18 (gate-per-lane, in-register
// epilogue, 8-block groups, proven counter protocol).

struct LstmP {
  const int* ids;
  const float* emb;            // f32 embedding table (cvt to bf16 in-kernel)
  const unsigned short* Wih;   // bf16 ws cache [2048,256]
  const unsigned short* Whh;   // bf16 ws cache [2048,512]
  const float* bias;           // f32 [2048]
  unsigned short* h0;          // bf16 double buffer base (2 * nh)
  float* c;                    // f32 [N,512] final-c output
  int T;
  int nh;                      // N*512
};

__device__ unsigned g_cnt[42*32];   // per-group step counters, 128B apart

__device__ __forceinline__ float bf2f(unsigned short x){
  union { unsigned u; float f; } v; v.u = ((unsigned)x) << 16; return v.f;
}
__device__ __forceinline__ unsigned short f2bf(float f){
  union { float f; unsigned u; } v; v.f = f;
  unsigned u = v.u;
  return (unsigned short)((u + 0x7fffu + ((u >> 16) & 1u)) >> 16);
}
__device__ __forceinline__ short8 cvt8(const float* p){
  f32x4 x = *(const f32x4*)p;
  f32x4 y = *(const f32x4*)(p + 4);
  short8 r;
  r[0]=(short)f2bf(x[0]); r[1]=(short)f2bf(x[1]); r[2]=(short)f2bf(x[2]); r[3]=(short)f2bf(x[3]);
  r[4]=(short)f2bf(y[0]); r[5]=(short)f2bf(y[1]); r[6]=(short)f2bf(y[2]); r[7]=(short)f2bf(y[3]);
  return r;
}
// Fast activations (R18-proven): v_exp_f32/v_rcp_f32, ~1e-7/step, << threshold.
__device__ __forceinline__ float sigm(float x){
  return __builtin_amdgcn_rcpf(1.0f + __builtin_amdgcn_exp2f(-1.44269504f*x));
}
__device__ __forceinline__ float tanh_f(float x){
  return 1.0f - 2.0f*__builtin_amdgcn_rcpf(1.0f + __builtin_amdgcn_exp2f(2.88539008f*x));
}

__global__ void zero_ws_kernel(uint4* p, int n){
  int i = blockIdx.x*256 + threadIdx.x;
  if (i < n){ uint4 z; z.x=0u; z.y=0u; z.z=0u; z.w=0u; p[i]=z; }
}

__global__ void zero_cnt_kernel(){
  for (int i = threadIdx.x; i < 42*32; i += 256) g_cnt[i] = 0u;
}

// f32 -> bf16 (RNE), 8 elems/thread. (R3-proven cache bit-match.)
__global__ __launch_bounds__(256) void cvt_kernel(const float* src, unsigned short* dst, int n8){
  int i = blockIdx.x*256 + threadIdx.x;
  if (i < n8){
    *(short8*)(dst + (size_t)i*8) = cvt8(src + (size_t)i*8);
  }
}

// Persistent kernel: block = one (lstm, mb32, jt64) tile for all T steps.
// Per step: group wait -> issue 8x16B coherent h loads (regs) -> phase1
// (emb x Wih, loads in flight) -> vmcnt(0) -> LDS deposit -> phase2 (h x Whh)
// -> in-register epilogue -> 16B coherent h store -> drain -> barrier -> release.
__global__ __launch_bounds__(256, 2) void lstm_persist(LstmP sc, LstmP cm, LstmP is_)
{
  __shared__ unsigned short hs[32][512];   // 32 KB staged h slab (swizzled)
  __shared__ unsigned short sh_h[32][72];  // h shuttle, padded rows (16B-aligned: 144B)

  LstmP P; int tile, grp;
  {
    int idx = blockIdx.x;
    if (idx < 160){ P = sc;  tile = idx;        grp = tile >> 3; }
    else if (idx < 320){ P = cm;  tile = idx - 160;  grp = 20 + (tile >> 3); }
    else { P = is_; tile = idx - 320;  grp = 40 + (tile >> 3); }
  }
  const int tid  = threadIdx.x;
  const int w    = tid >> 6;       // wave = j-subslice owner (all 4 gates)
  const int lane = tid & 63;
  const int l15  = lane & 15;
  const int q    = lane >> 4;
  const int mb = tile >> 3, jt = tile & 7;
  const int m0 = mb*32, j0 = jt*64;
  const int jw = j0 + w*16;
  const int T = P.T;
  unsigned* cgp = &g_cnt[grp*32];
  const int xr = (l15 & 7) << 3;   // hs row-XOR swizzle (per-lane const, in shorts)

  const int* idrow[2];             // ids row per A-fragment row
  #pragma unroll
  for (int mi=0; mi<2; ++mi){
    int m = m0 + mi*16 + l15;
    idrow[mi] = P.ids + (size_t)m*T;
  }
  const unsigned short* bg1[4];    // bf16 Wih rows: gate g, unit jw+l15
  const unsigned short* bg2[4];
  float bvv[4];
  #pragma unroll
  for (int g=0; g<4; ++g){
    int n = g*Hh + jw + l15;
    bg1[g] = P.Wih + (size_t)n*E  + q*8;
    bg2[g] = P.Whh + (size_t)n*Hh + q*8;
    bvv[g] = P.bias[n];
  }

  float cc[8];                     // persistent cell state: (mi,r) -> row mi*16+q*4+r, col jw+l15
  #pragma unroll
  for (int i=0;i<8;++i) cc[i] = 0.f;

  for (int t = 0; t < T; ++t){
    const unsigned short* h_in  = P.h0 + (size_t)(t&1)*P.nh;
    unsigned short*       h_out = P.h0 + (size_t)((t+1)&1)*P.nh;

    f32x4 acc[2][4];
    #pragma unroll
    for (int i=0;i<2;++i)
      #pragma unroll
      for (int g=0;g<4;++g) acc[i][g] = (f32x4){0.f,0.f,0.f,0.f};

    // Wait for h(t), then ISSUE the coherent staging loads (16B each) so they
    // fly during phase-1. t==0: h is zeros -> phase 2 skipped entirely.
    uint4v stg[8];
    if (t > 0){
      if (tid == 0){
        unsigned tgt = 8u * (unsigned)t;
        long guard = 0;
        while (__hip_atomic_load(cgp, __ATOMIC_RELAXED, __HIP_MEMORY_SCOPE_AGENT) < tgt){
          __builtin_amdgcn_s_sleep(1);
          if (++guard > 2000000L) break;   // convert protocol bug -> wrong answer, not hang
        }
      }
      __syncthreads();
      asm volatile("" ::: "memory");       // compiler-only fence (no cache ops)

      const unsigned short* base = h_in + (size_t)m0*Hh;
      #pragma unroll
      for (int i=0;i<8;++i){
        int d = (tid + 256*i + (jt<<8)) & 2047;   // per-group rotation, full cover
        const void* ap = (const void*)(base + (size_t)d*8);
        asm volatile("global_load_dwordx4 %0, %1, off sc0 sc1"
                     : "=v"(stg[i]) : "v"(ap) : "memory");
      }
    }

    // Phase 1: K=0..255, x = emb (cvt f32->bf16), W = Wih. Staging loads in flight.
    const float* ap1[2];
    #pragma unroll
    for (int mi=0; mi<2; ++mi){
      int id = idrow[mi][t];
      ap1[mi] = P.emb + (size_t)id*E + q*8;
    }
    #pragma unroll 2
    for (int kc=0; kc<8; ++kc){
      short8 a[2], b[4];
      #pragma unroll
      for (int mi=0;mi<2;++mi) a[mi] = cvt8(ap1[mi] + kc*32);
      #pragma unroll
      for (int g=0;g<4;++g) b[g] = *(const short8*)(bg1[g] + kc*32);
      #pragma unroll
      for (int mi=0;mi<2;++mi)
        #pragma unroll
        for (int g=0;g<4;++g)
          acc[mi][g] = __builtin_amdgcn_mfma_f32_16x16x32_bf16(a[mi], b[g], acc[mi][g], 0,0,0);
    }

    if (t > 0){
      // Drain staging loads, deposit to swizzled LDS (16B-unit swizzle:
      // chunk cp -> cp ^ (row&7); identical permutation to proven qword form).
      asm volatile("s_waitcnt vmcnt(0)" ::: "memory");
      #pragma unroll
      for (int i=0;i<8;++i){
        int d = (tid + 256*i + (jt<<8)) & 2047;
        int row = d >> 6, cp = d & 63;
        *(uint4v*)&hs[row][(cp ^ (row & 7)) << 3] = stg[i];
      }
      __syncthreads();

      // Phase 2: K=256..767, x = h (bf16, from swizzled LDS), W = Whh
      #pragma unroll 2
      for (int kc=0; kc<16; ++kc){
        short8 a[2], b[4];
        #pragma unroll
        for (int mi=0;mi<2;++mi)
          a[mi] = *(const short8*)&hs[mi*16 + l15][(kc*32 + q*8) ^ xr];
        #pragma unroll
        for (int g=0;g<4;++g) b[g] = *(const short8*)(bg2[g] + kc*32);
        #pragma unroll
        for (int mi=0;mi<2;++mi)
          #pragma unroll
          for (int g=0;g<4;++g)
            acc[mi][g] = __builtin_amdgcn_mfma_f32_16x16x32_bf16(a[mi], b[g], acc[mi][g], 0,0,0);
      }
    }

    // In-register epilogue: C layout (m89-verified) row=q*4+r, col=l15 -> this
    // lane's element (mi*16+q*4+r, jw+l15) has all 4 gates in acc[mi][g][r].
    #pragma unroll
    for (int mi=0;mi<2;++mi)
      #pragma unroll
      for (int r=0;r<4;++r){
        float zi = acc[mi][0][r] + bvv[0];
        float zf = acc[mi][1][r] + bvv[1];
        float zg = acc[mi][2][r] + bvv[2];
        float zo = acc[mi][3][r] + bvv[3];
        float cn = sigm(zf)*cc[mi*4+r] + sigm(zi)*tanh_f(zg);
        float hn = sigm(zo)*tanh_f(cn);
        cc[mi*4+r] = cn;
        sh_h[mi*16 + q*4 + r][w*16 + l15] = f2bf(hn);
      }
    __syncthreads();

    // Shuttle -> one 16B coherent h store per thread (32 rows x 4 oct-chunks... 8 octs).
    {
      int m = tid >> 3, oct = tid & 7;
      uint4v pk = *(const uint4v*)&sh_h[m][oct*8];
      void* ap = (void*)(h_out + (size_t)(m0+m)*Hh + j0 + oct*8);
      asm volatile("global_store_dwordx4 %0, %1, off sc0 sc1"
                   :: "v"(ap), "v"(pk) : "memory");
    }

    // Release step t: drain own write-through stores, converge, tid0 counts.
    asm volatile("s_waitcnt vmcnt(0)" ::: "memory");
    __syncthreads();
    if (tid == 0)
      __hip_atomic_fetch_add(cgp, 1u, __ATOMIC_RELAXED, __HIP_MEMORY_SCOPE_AGENT);
  }

  // Final c to global (plain stores; dispatch boundary publishes to out_kernel).
  #pragma unroll
  for (int mi=0;mi<2;++mi)
    #pragma unroll
    for (int r=0;r<4;++r)
      P.c[(size_t)(m0 + mi*16 + q*4 + r)*Hh + jw + l15] = cc[mi*4+r];
}

// Output kernel (R16-proven). 256 blocks: (b, kind, u-half). v-row in LDS,
// hm via shfl-reduce (1 barrier), u-dot with 4 independent accumulators.
__global__ __launch_bounds__(256) void out_kernel(
    const unsigned short* hsc, const unsigned short* hcm, const unsigned short* his,
    const float* csc, const float* ccm, const float* cis,
    const float* Wmh, const float* bmh, const float* Wmc, const float* bmc,
    const float* Wfh, const float* bfh, const float* Wfc, const float* bfc,
    float* out)
{
  const int b    = blockIdx.x >> 2;
  const int kind = (blockIdx.x >> 1) & 1;
  const int half = blockIdx.x & 1;
  const int tid  = threadIdx.x;
  const int w = tid >> 6, lane = tid & 63;
  const float* Wm = kind ? Wmc : Wmh;
  const float* bm = kind ? bmc : bmh;
  const float* Wf = kind ? Wfc : Wfh;
  const float* bf = kind ? bfc : bfh;

  __shared__ float vis[512];
  __shared__ float wred[10][4];
  __shared__ float hmb[10];

  for (int k = tid; k < 512; k += 256)
    vis[k] = kind ? cis[(size_t)b*512 + k] : bf2f(his[(size_t)b*512 + k]);

  float pn[10];
  #pragma unroll
  for (int nc=0; nc<10; ++nc){
    size_t n = (size_t)b*10 + nc;
    float a = 0.f;
    #pragma unroll
    for (int kk=0; kk<2; ++kk){
      int k = tid + kk*256;
      float v1 = kind ? csc[n*512+k] : bf2f(hsc[n*512+k]);
      float v2 = kind ? ccm[n*512+k] : bf2f(hcm[n*512+k]);
      a += Wm[k]*v1 + Wm[512+k]*v2;
    }
    pn[nc] = a;
  }
  #pragma unroll
  for (int nc=0; nc<10; ++nc){
    float v = pn[nc];
    #pragma unroll
    for (int off=32; off; off>>=1) v += __shfl_down(v, off);
    if (lane == 0) wred[nc][w] = v;
  }
  __syncthreads();
  if (tid < 10) hmb[tid] = wred[tid][0] + wred[tid][1] + wred[tid][2] + wred[tid][3] + bm[0];
  __syncthreads();

  const int u = tid + 256*half;
  const float* wr = Wf + (size_t)u*522;
  float a0 = bf[u], a1 = 0.f, a2 = 0.f, a3 = 0.f;
  #pragma unroll
  for (int k=0; k<10; ++k) a0 += wr[k]*hmb[k];
  #pragma unroll 4
  for (int k=0; k<512; k+=4){
    a0 += wr[10+k] * vis[k];
    a1 += wr[11+k] * vis[k+1];
    a2 += wr[12+k] * vis[k+2];
    a3 += wr[13+k] * vis[k+3];
  }
  out[(size_t)kind*32768 + (size_t)b*512 + u] = (a0+a1) + (a2+a3);
}

extern "C" void kernel_launch(void* const* d_in, const int* in_sizes, int n_in,
                              void* d_out, int out_size, void* d_ws, size_t ws_size,
                              hipStream_t stream) {
  const int* comments = (const int*)d_in[0];
  const int* cm_ids   = (const int*)d_in[1];
  const int* issue    = (const int*)d_in[2];
  const float* emb_sc = (const float*)d_in[3];
  const float* emb_cm = (const float*)d_in[4];
  const float* emb_is = (const float*)d_in[5];
  const float* Wih_sc = (const float*)d_in[6];
  const float* Whh_sc = (const float*)d_in[7];
  const float* b_sc   = (const float*)d_in[8];
  const float* Wih_cm = (const float*)d_in[9];
  const float* Whh_cm = (const float*)d_in[10];
  const float* b_cm   = (const float*)d_in[11];
  const float* Wih_is = (const float*)d_in[12];
  const float* Whh_is = (const float*)d_in[13];
  const float* b_is   = (const float*)d_in[14];
  const float* Wmh = (const float*)d_in[15];
  const float* bmh = (const float*)d_in[16];
  const float* Wmc = (const float*)d_in[17];
  const float* bmc = (const float*)d_in[18];
  const float* Wfh = (const float*)d_in[19];
  const float* bfh = (const float*)d_in[20];
  const float* Wfc = (const float*)d_in[21];
  const float* bfc = (const float*)d_in[22];

  // Workspace (14.94 MB total == R3's proven extent; layout unchanged)
  char* p = (char*)d_ws;
  unsigned short* hb_sc = (unsigned short*)p; p += (size_t)2*640*512*2;
  unsigned short* hb_cm = (unsigned short*)p; p += (size_t)2*640*512*2;
  unsigned short* hb_is = (unsigned short*)p; p += (size_t)2*64*512*2;
  float* c_sc = (float*)p; p += (size_t)640*512*4;
  float* c_cm = (float*)p; p += (size_t)640*512*4;
  float* c_is = (float*)p; p += (size_t)64*512*4;
  size_t zero_bytes = (size_t)(p - (char*)d_ws);
  unsigned short* Wih_sc_b = (unsigned short*)p; p += (size_t)2048*256*2;
  unsigned short* Whh_sc_b = (unsigned short*)p; p += (size_t)2048*512*2;
  unsigned short* Wih_cm_b = (unsigned short*)p; p += (size_t)2048*256*2;
  unsigned short* Whh_cm_b = (unsigned short*)p; p += (size_t)2048*512*2;
  unsigned short* Wih_is_b = (unsigned short*)p; p += (size_t)2048*256*2;
  unsigned short* Whh_is_b = (unsigned short*)p; p += (size_t)2048*512*2;

  int n4 = (int)(zero_bytes/16);
  zero_ws_kernel<<<(n4+255)/256, 256, 0, stream>>>((uint4*)d_ws, n4);
  zero_cnt_kernel<<<1, 256, 0, stream>>>();

  const int nih8 = 2048*256/8, nhh8 = 2048*512/8;
  cvt_kernel<<<(nih8+255)/256, 256, 0, stream>>>(Wih_sc, Wih_sc_b, nih8);
  cvt_kernel<<<(nhh8+255)/256, 256, 0, stream>>>(Whh_sc, Whh_sc_b, nhh8);
  cvt_kernel<<<(nih8+255)/256, 256, 0, stream>>>(Wih_cm, Wih_cm_b, nih8);
  cvt_kernel<<<(nhh8+255)/256, 256, 0, stream>>>(Whh_cm, Whh_cm_b, nhh8);
  cvt_kernel<<<(nih8+255)/256, 256, 0, stream>>>(Wih_is, Wih_is_b, nih8);
  cvt_kernel<<<(nhh8+255)/256, 256, 0, stream>>>(Whh_is, Whh_is_b, nhh8);

  LstmP Psc = { comments, emb_sc, Wih_sc_b, Whh_sc_b, b_sc, hb_sc, c_sc, 128, 640*512 };
  LstmP Pcm = { cm_ids,   emb_cm, Wih_cm_b, Whh_cm_b, b_cm, hb_cm, c_cm,  64, 640*512 };
  LstmP Pis = { issue,    emb_is, Wih_is_b, Whh_is_b, b_is, hb_is, c_is,  32,  64*512 };
  lstm_persist<<<336, 256, 0, stream>>>(Psc, Pcm, Pis);

  // Final h states in buffer 0 for all three (T even for sc/cm/is).
  out_kernel<<<256, 256, 0, stream>>>(hb_sc, hb_cm, hb_is, c_sc, c_cm, c_is,
                                      Wmh, bmh, Wmc, bmc, Wfh, bfh, Wfc, bfc,
                                      (float*)d_out);
}